// Round 14
// baseline (1481.095 us; speedup 1.0000x reference)
//
#include <hip/hip_runtime.h>

// GraphSAGE 2-layer encoder, fp32 compute, bf16-compressed tables.
// Identity: agg@Wl^T = mean_{src}(x[src]@Wl^T)  (mean commutes with linear).
// Pipeline:
//   bucket_pass: bin edges by (dst>>9, src-range quarter) -> 784 dense lists
//   per layer: y = x@Wl^T (bf16), z = x@Wr^T + b (bf16)        [yz_gemm]
//              gather_lds: one block per dst-bucket, fp32 accumulation in LDS
//                (130KB), all 196 blocks co-resident sweeping the 4 src-ranges
//                IN PHASE -> live y-slice is 3.2MB, L2-resident per XCD.
// h1 stored bf16, consumed bf16 by GEMM-2. Degree counted in LDS during
// accumulation (no slot table, no cnt array, no slots_pass).

#define N_NODES 100000
#define N_EDGES 1600000
#define D 64

#define B_SHIFT 9                                   // 512 nodes per bucket
#define NBKT ((N_NODES + (1 << B_SHIFT) - 1) >> B_SHIFT)   // 196
#define NBIN (NBKT * 4)                             // 784 (bucket x src-range)
#define ECAP 3000          // per-bin cap; mean 2041, sigma~45 -> +21 sigma
#define P1_BLOCK 1024
#define P1_EDGES 4096
#define P1_GRID ((N_EDGES + P1_EDGES - 1) / P1_EDGES)      // 391

typedef unsigned int uint32;

__device__ __forceinline__ uint32 f2bf_rne(float f) {
    uint32 u = __float_as_uint(f);
    return (u + 0x7fffu + ((u >> 16) & 1u)) >> 16;
}

// ---- pass 1: bin edges by (dst-bucket, src-range); entry = (dst&511)<<17 | src ----
__global__ __launch_bounds__(P1_BLOCK) void bucket_pass(const int* __restrict__ src,
                                                        const int* __restrict__ dst,
                                                        int* __restrict__ bcnt4,
                                                        int* __restrict__ ebuf) {
    __shared__ int lcount[NBIN];
    __shared__ int lbase[NBIN];
    const int tid = threadIdx.x;
    for (int i = tid; i < NBIN; i += P1_BLOCK) lcount[i] = 0;
    __syncthreads();

    const int i0 = blockIdx.x * P1_EDGES + tid * 4;
    const bool v0 = (i0 < N_EDGES);              // E%4==0 -> never partial
    int4 s0, d0;
    if (v0) { s0 = *(const int4*)(src + i0); d0 = *(const int4*)(dst + i0); }

#define RQ(S) ((S) >= 50000 ? ((S) >= 75000 ? 3 : 2) : ((S) >= 25000 ? 1 : 0))
#define BIN(S, DV) ((((DV) >> B_SHIFT) << 2) | RQ(S))
    if (v0) {
        atomicAdd(&lcount[BIN(s0.x, d0.x)], 1);
        atomicAdd(&lcount[BIN(s0.y, d0.y)], 1);
        atomicAdd(&lcount[BIN(s0.z, d0.z)], 1);
        atomicAdd(&lcount[BIN(s0.w, d0.w)], 1);
    }
    __syncthreads();
    for (int i = tid; i < NBIN; i += P1_BLOCK) {   // reserve dense ranges
        int c = lcount[i];
        lbase[i] = c ? atomicAdd(&bcnt4[i], c) : 0;
        lcount[i] = 0;
    }
    __syncthreads();

#define PUT(S, DV)                                                     \
    {                                                                  \
        int b_ = BIN(S, DV);                                           \
        int p_ = atomicAdd(&lcount[b_], 1) + lbase[b_];                \
        if (p_ < ECAP)                                                 \
            ebuf[b_ * ECAP + p_] = (((DV) & 511) << 17) | (S);         \
    }
    if (v0) { PUT(s0.x, d0.x); PUT(s0.y, d0.y); PUT(s0.z, d0.z); PUT(s0.w, d0.w); }
#undef PUT
#undef BIN
#undef RQ
}

// -------- dense part: y[i] = x@Wl^T (bf16), z[i] = x@Wr^T + b (bf16) --------
// 64 nodes x 128 outputs per block; Ws reads broadcast, As reads 2-way (free).
#define GEMM_TM 64
#define AS_PAD 68
template <int IN_BF16>
__global__ __launch_bounds__(256) void yz_gemm(const void* __restrict__ featv,
                                               const float* __restrict__ Wl,
                                               const float* __restrict__ Wr,
                                               const float* __restrict__ bias,
                                               uint32* __restrict__ ybf,
                                               uint32* __restrict__ zbf) {
    __shared__ float Ws[D][128];
    __shared__ float As[D][AS_PAD];
    const int t = threadIdx.x;

    {
        int j = t & 127;
        int h = t >> 7;
        const float* wsrc = (j < D) ? &Wl[j * D] : &Wr[(j - D) * D];
#pragma unroll
        for (int q = 0; q < 8; ++q) {
            int k = h * 32 + q * 4;
            float4 v = *reinterpret_cast<const float4*>(&wsrc[k]);
            Ws[k + 0][j] = v.x; Ws[k + 1][j] = v.y;
            Ws[k + 2][j] = v.z; Ws[k + 3][j] = v.w;
        }
    }
    const int base = blockIdx.x * GEMM_TM;
    {
        int n = t >> 2;
        int node = base + n;
        if (node >= N_NODES) node = N_NODES - 1;   // clamp; stores guarded
        int kk = (t & 3) * 16;
        if (IN_BF16) {
            const uint32* frow = (const uint32*)featv + (size_t)node * 32 + (t & 3) * 8;
            uint4 v0 = *reinterpret_cast<const uint4*>(frow);
            uint4 v1 = *reinterpret_cast<const uint4*>(frow + 4);
            uint32 u[8] = {v0.x, v0.y, v0.z, v0.w, v1.x, v1.y, v1.z, v1.w};
#pragma unroll
            for (int q = 0; q < 8; ++q) {
                As[kk + 2 * q + 0][n] = __uint_as_float(u[q] << 16);
                As[kk + 2 * q + 1][n] = __uint_as_float(u[q] & 0xffff0000u);
            }
        } else {
            const float* feat = (const float*)featv;
#pragma unroll
            for (int q = 0; q < 4; ++q) {
                int k2 = kk + q * 4;
                float4 v = *reinterpret_cast<const float4*>(&feat[node * D + k2]);
                As[k2 + 0][n] = v.x; As[k2 + 1][n] = v.y;
                As[k2 + 2][n] = v.z; As[k2 + 3][n] = v.w;
            }
        }
    }
    __syncthreads();

    const int j0 = (t >> 4) * 8;   // 0..120; 4 values per wave (broadcast reads)
    const int n0 = (t & 15) * 4;   // 16 consecutive 16B groups per wave
    float acc[4][8];
#pragma unroll
    for (int i = 0; i < 4; ++i)
#pragma unroll
        for (int j = 0; j < 8; ++j) acc[i][j] = 0.f;

#pragma unroll 4
    for (int k = 0; k < D; ++k) {
        float4 w0 = *reinterpret_cast<const float4*>(&Ws[k][j0]);
        float4 w1 = *reinterpret_cast<const float4*>(&Ws[k][j0 + 4]);
        float4 a4 = *reinterpret_cast<const float4*>(&As[k][n0]);
        float a[4] = {a4.x, a4.y, a4.z, a4.w};
        float w[8] = {w0.x, w0.y, w0.z, w0.w, w1.x, w1.y, w1.z, w1.w};
#pragma unroll
        for (int i = 0; i < 4; ++i)
#pragma unroll
            for (int j = 0; j < 8; ++j) acc[i][j] += a[i] * w[j];
    }

    const bool isY = (j0 < D);
    const int zj = isY ? j0 : (j0 - D);
    float bj[8];
#pragma unroll
    for (int j = 0; j < 8; ++j) bj[j] = isY ? 0.f : bias[zj + j];
    uint32* dstT = isY ? ybf : zbf;

#pragma unroll
    for (int i = 0; i < 4; ++i) {
        int node = base + n0 + i;
        if (node < N_NODES) {
            float v0 = acc[i][0] + bj[0], v1 = acc[i][1] + bj[1];
            float v2 = acc[i][2] + bj[2], v3 = acc[i][3] + bj[3];
            float v4 = acc[i][4] + bj[4], v5 = acc[i][5] + bj[5];
            float v6 = acc[i][6] + bj[6], v7 = acc[i][7] + bj[7];
            uint32 p0 = f2bf_rne(v0) | (f2bf_rne(v1) << 16);
            uint32 p1 = f2bf_rne(v2) | (f2bf_rne(v3) << 16);
            uint32 p2 = f2bf_rne(v4) | (f2bf_rne(v5) << 16);
            uint32 p3 = f2bf_rne(v6) | (f2bf_rne(v7) << 16);
            *reinterpret_cast<uint4*>(&dstT[node * (D / 2) + (zj >> 1)]) =
                make_uint4(p0, p1, p2, p3);
        }
    }
}

// -------- sparse part: block = dst-bucket, fp32 accumulate in LDS --------
// 196 blocks x 1024 threads, co-resident (1/CU, 130KB LDS). Sweep src-ranges
// q=0..3 in phase. Per edge: 32 lanes read the 128B y row (lane=uint u),
// 2 LDS f32 atomics each. Bank layout: feat 2u -> acc[dl*64+u] (bank u),
// feat 2u+1 -> acc[dl*64+u+32] (same bank, serialized 2nd op) -> conflict-free.
template <int RELU, int OUT_BF16>
__global__ __launch_bounds__(1024) void gather_lds(const uint32* __restrict__ ybf,
                                                   const uint32* __restrict__ zbf,
                                                   const int* __restrict__ ebuf,
                                                   const int* __restrict__ bcnt4,
                                                   void* __restrict__ outv) {
    __shared__ float accS[512 * 64];   // 128 KB
    __shared__ int degS[512];          // 2 KB
    const int b = blockIdx.x;
    const int t = threadIdx.x;
    for (int i = t; i < 512 * 64; i += 1024) accS[i] = 0.f;
    if (t < 512) degS[t] = 0;
    __syncthreads();

    const int wv = t >> 6;             // 16 waves
    const int lane = t & 63;
    const int eg = lane >> 5;          // 2 edge-groups per wave
    const int u = lane & 31;           // uint index within 128B row
    const int istart = wv * 2 + eg;    // 0..31

#define EDGE(E)                                                          \
    {                                                                    \
        const int d_ = (int)(((uint32)(E)) >> 17);                       \
        const uint32 y_ = ybf[(size_t)((E) & 0x1FFFF) * 32 + u];         \
        if (u == 0) atomicAdd(&degS[d_], 1);                             \
        atomicAdd(&accS[d_ * 64 + u], __uint_as_float(y_ << 16));        \
        atomicAdd(&accS[d_ * 64 + u + 32],                               \
                  __uint_as_float(y_ & 0xffff0000u));                    \
    }

#pragma unroll
    for (int q = 0; q < 4; ++q) {
        const int li = (b << 2) + q;
        int qc = bcnt4[li];
        if (qc > ECAP) qc = ECAP;
        const int* eb = ebuf + (size_t)li * ECAP;
        int i = istart;
        for (; i + 96 < qc; i += 128) {            // 4 edges in flight per lane-group
            const int e0 = eb[i], e1 = eb[i + 32], e2 = eb[i + 64], e3 = eb[i + 96];
            EDGE(e0); EDGE(e1); EDGE(e2); EDGE(e3);
        }
        for (; i < qc; i += 32) {                  // tail
            const int e0 = eb[i];
            EDGE(e0);
        }
        __syncthreads();                           // phase boundary (also final fence)
    }
#undef EDGE

    // flush: out[node] = act(z + acc/deg)
    const int n0 = b << B_SHIFT;
    for (int p = t; p < 512 * 32; p += 1024) {
        const int dl = p >> 5, uu = p & 31;
        const int node = n0 + dl;
        if (node < N_NODES) {
            const float invd = 1.0f / fmaxf((float)degS[dl], 1.0f);
            const uint32 zu = zbf[(size_t)node * 32 + uu];
            float o0 = __uint_as_float(zu << 16)         + invd * accS[dl * 64 + uu];
            float o1 = __uint_as_float(zu & 0xffff0000u) + invd * accS[dl * 64 + uu + 32];
            if (RELU) { o0 = fmaxf(o0, 0.f); o1 = fmaxf(o1, 0.f); }
            if (OUT_BF16) {
                ((uint32*)outv)[(size_t)node * 32 + uu] =
                    f2bf_rne(o0) | (f2bf_rne(o1) << 16);
            } else {
                float2 o; o.x = o0; o.y = o1;
                reinterpret_cast<float2*>(outv)[(size_t)node * 32 + uu] = o;
            }
        }
    }
}

extern "C" void kernel_launch(void* const* d_in, const int* in_sizes, int n_in,
                              void* d_out, int out_size, void* d_ws, size_t ws_size,
                              hipStream_t stream) {
    const float* x   = (const float*)d_in[0];
    const int*   ei  = (const int*)d_in[1];
    const float* W1l = (const float*)d_in[2];
    const float* b1  = (const float*)d_in[3];
    const float* W1r = (const float*)d_in[4];
    const float* W2l = (const float*)d_in[5];
    const float* b2  = (const float*)d_in[6];
    const float* W2r = (const float*)d_in[7];
    float* out = (float*)d_out;

    const int* src = ei;            // edge_index[0]
    const int* dst = ei + N_EDGES;  // edge_index[1]

    // Workspace (~47.8 MB):
    //   bcnt4 [0, 3136)
    //   ebuf  [3200, +9.408MB)     784 bins x 3000 x 4B (persistent adjacency)
    //   ybf   [9411200, +12.8MB)   bf16 y table, 128B/row
    //   zbf   [22211200, +12.8MB)  bf16 z table, 128B/row
    //   h1b   [35011200, +12.8MB)  bf16 h1 table, 128B/row
    char* ws = (char*)d_ws;
    int*    bcnt4 = (int*)ws;
    int*    ebuf  = (int*)(ws + 3200);
    uint32* ybf   = (uint32*)(ws + 9411200);
    uint32* zbf   = (uint32*)(ws + 22211200);
    uint32* h1b   = (uint32*)(ws + 35011200);

    // --- adjacency build (one pass) ---
    (void)hipMemsetAsync(bcnt4, 0, NBIN * 4, stream);
    bucket_pass<<<P1_GRID, P1_BLOCK, 0, stream>>>(src, dst, bcnt4, ebuf);

    int gemm_grid = (N_NODES + GEMM_TM - 1) / GEMM_TM;   // 1563

    // layer 1 (fp32 x in, bf16 h1 out)
    yz_gemm<0><<<gemm_grid, 256, 0, stream>>>(x, W1l, W1r, b1, ybf, zbf);
    gather_lds<1, 1><<<NBKT, 1024, 0, stream>>>(ybf, zbf, ebuf, bcnt4, h1b);
    // layer 2 (bf16 h1 in, fp32 out)
    yz_gemm<1><<<gemm_grid, 256, 0, stream>>>(h1b, W2l, W2r, b2, ybf, zbf);
    gather_lds<0, 0><<<NBKT, 1024, 0, stream>>>(ybf, zbf, ebuf, bcnt4, out);
}

// Round 15
// 219.919 us; speedup vs baseline: 6.7347x; 6.7347x over previous
//
#include <hip/hip_runtime.h>

// GraphSAGE 2-layer encoder, fp32 compute, bf16-compressed tables.
// Identity: agg@Wl^T = mean_{src}(x[src]@Wl^T)  (mean commutes with linear).
// Pipeline:
//   adjacency: 2-level bucket scatter -> padded slot table (L2-local writes)
//   per layer: y = x@Wl^T (bf16 128B rows), z = x@Wr^T + b (bf16 128B rows)
//              out[i] = act( z[i] + inv_deg[i] * sum_{s in N(i)} y[s] )
//   gather: wave/node, half-wave even/odd slots, lane = bf16-pair -> 256B/round.
// h1 (layer-1 output) is stored bf16 and consumed bf16 by GEMM-2.
// NOTES: nontemporal hints REGRESSED (r11: gather 66->78us, FETCH unchanged).
//        LDS-atomic bucket gather REGRESSED 10x (r14: 102M LDS atomics serialize).
//        Plane-split gather REGRESSED (r7); phased VGPR gather REGRESSED (r9).
//        This wave-per-node 16-slot structure is the measured optimum.

#define N_NODES 100000
#define N_EDGES 1600000
#define D 64
#define SLOT_CAP 48        // deg ~ Poisson(16); P(deg>48) ~ 1e-6

#define B_SHIFT 9                                   // 512 nodes per bucket
#define NBKT ((N_NODES + (1 << B_SHIFT) - 1) >> B_SHIFT)   // 196
#define BUCKET_CAP 12288
#define P1_BLOCK 1024
#define P1_EDGES 4096      // 21 entries/bucket/block -> 84B write runs
#define P1_GRID ((N_EDGES + P1_EDGES - 1) / P1_EDGES)      // 391

typedef unsigned int uint32;

__device__ __forceinline__ uint32 f2bf_rne(float f) {
    uint32 u = __float_as_uint(f);
    return (u + 0x7fffu + ((u >> 16) & 1u)) >> 16;
}

// ---- pass 1: bin edges by dst bucket; entry = ((dst&511)<<20) | src ----
__global__ __launch_bounds__(P1_BLOCK) void bucket_pass(const int* __restrict__ src,
                                                        const int* __restrict__ dst,
                                                        int* __restrict__ bcnt,
                                                        int* __restrict__ buf) {
    __shared__ int lcount[NBKT];
    __shared__ int lbase[NBKT];
    const int tid = threadIdx.x;
    for (int i = tid; i < NBKT; i += P1_BLOCK) lcount[i] = 0;
    __syncthreads();

    const int i0 = blockIdx.x * P1_EDGES + tid * 4;
    const bool v0 = (i0 < N_EDGES);              // E%4==0 -> never partial
    int4 s0, d0;
    if (v0) { s0 = *(const int4*)(src + i0); d0 = *(const int4*)(dst + i0); }

    if (v0) {
        atomicAdd(&lcount[d0.x >> B_SHIFT], 1);
        atomicAdd(&lcount[d0.y >> B_SHIFT], 1);
        atomicAdd(&lcount[d0.z >> B_SHIFT], 1);
        atomicAdd(&lcount[d0.w >> B_SHIFT], 1);
    }
    __syncthreads();
    for (int i = tid; i < NBKT; i += P1_BLOCK) {   // reserve dense ranges
        int c = lcount[i];
        lbase[i] = c ? atomicAdd(&bcnt[i], c) : 0;
        lcount[i] = 0;
    }
    __syncthreads();

#define PUT(S, DV)                                                     \
    {                                                                  \
        int b_ = (DV) >> B_SHIFT;                                      \
        int p_ = atomicAdd(&lcount[b_], 1) + lbase[b_];                \
        if (p_ < BUCKET_CAP)                                           \
            buf[b_ * BUCKET_CAP + p_] = (((DV) & 511) << 20) | (S);    \
    }
    if (v0) { PUT(s0.x, d0.x); PUT(s0.y, d0.y); PUT(s0.z, d0.z); PUT(s0.w, d0.w); }
#undef PUT
}

// ---- pass 2: one block per bucket -> slot table + degree (LDS-atomic ranks) ----
#define P2_BLOCK 1024
__global__ __launch_bounds__(P2_BLOCK) void slots_pass(const int* __restrict__ buf,
                                                       const int* __restrict__ bcnt,
                                                       int* __restrict__ cnt,
                                                       int* __restrict__ slots) {
    __shared__ int lcnt[1 << B_SHIFT];
    const int b = blockIdx.x;
    const int tid = threadIdx.x;
    for (int i = tid; i < (1 << B_SHIFT); i += P2_BLOCK) lcnt[i] = 0;
    __syncthreads();
    int count = bcnt[b];
    if (count > BUCKET_CAP) count = BUCKET_CAP;
    const int n0 = b << B_SHIFT;
    const int* eb = buf + b * BUCKET_CAP;
    for (int i = tid; i < count; i += P2_BLOCK) {
        int p = eb[i];
        int dl = ((unsigned)p) >> 20;
        int s = p & 0xFFFFF;
        int r = atomicAdd(&lcnt[dl], 1);
        if (r < SLOT_CAP) slots[(n0 + dl) * SLOT_CAP + r] = s;
    }
    __syncthreads();
    for (int j = tid; j < (1 << B_SHIFT); j += P2_BLOCK) {
        int node = n0 + j;
        if (node < N_NODES) cnt[node] = lcnt[j];
    }
}

// -------- dense part: y[i] = x@Wl^T (bf16), z[i] = x@Wr^T + b (bf16) --------
// 64 nodes x 128 outputs per block; Ws reads broadcast, As reads 2-way (free).
// IN_BF16: feat rows are 32 uints (packed bf16 pairs) instead of 64 floats.
#define GEMM_TM 64
#define AS_PAD 68
template <int IN_BF16>
__global__ __launch_bounds__(256) void yz_gemm(const void* __restrict__ featv,
                                               const float* __restrict__ Wl,
                                               const float* __restrict__ Wr,
                                               const float* __restrict__ bias,
                                               uint32* __restrict__ ybf,
                                               uint32* __restrict__ zbf) {
    __shared__ float Ws[D][128];
    __shared__ float As[D][AS_PAD];
    const int t = threadIdx.x;

    {
        int j = t & 127;
        int h = t >> 7;
        const float* wsrc = (j < D) ? &Wl[j * D] : &Wr[(j - D) * D];
#pragma unroll
        for (int q = 0; q < 8; ++q) {
            int k = h * 32 + q * 4;
            float4 v = *reinterpret_cast<const float4*>(&wsrc[k]);
            Ws[k + 0][j] = v.x; Ws[k + 1][j] = v.y;
            Ws[k + 2][j] = v.z; Ws[k + 3][j] = v.w;
        }
    }
    const int base = blockIdx.x * GEMM_TM;
    {
        int n = t >> 2;
        int node = base + n;
        if (node >= N_NODES) node = N_NODES - 1;   // clamp; stores guarded
        int kk = (t & 3) * 16;
        if (IN_BF16) {
            const uint32* frow = (const uint32*)featv + (size_t)node * 32 + (t & 3) * 8;
            uint4 v0 = *reinterpret_cast<const uint4*>(frow);
            uint4 v1 = *reinterpret_cast<const uint4*>(frow + 4);
            uint32 u[8] = {v0.x, v0.y, v0.z, v0.w, v1.x, v1.y, v1.z, v1.w};
#pragma unroll
            for (int q = 0; q < 8; ++q) {
                As[kk + 2 * q + 0][n] = __uint_as_float(u[q] << 16);
                As[kk + 2 * q + 1][n] = __uint_as_float(u[q] & 0xffff0000u);
            }
        } else {
            const float* feat = (const float*)featv;
#pragma unroll
            for (int q = 0; q < 4; ++q) {
                int k2 = kk + q * 4;
                float4 v = *reinterpret_cast<const float4*>(&feat[node * D + k2]);
                As[k2 + 0][n] = v.x; As[k2 + 1][n] = v.y;
                As[k2 + 2][n] = v.z; As[k2 + 3][n] = v.w;
            }
        }
    }
    __syncthreads();

    const int j0 = (t >> 4) * 8;   // 0..120; 4 values per wave (broadcast reads)
    const int n0 = (t & 15) * 4;   // 16 consecutive 16B groups per wave
    float acc[4][8];
#pragma unroll
    for (int i = 0; i < 4; ++i)
#pragma unroll
        for (int j = 0; j < 8; ++j) acc[i][j] = 0.f;

#pragma unroll 4
    for (int k = 0; k < D; ++k) {
        float4 w0 = *reinterpret_cast<const float4*>(&Ws[k][j0]);
        float4 w1 = *reinterpret_cast<const float4*>(&Ws[k][j0 + 4]);
        float4 a4 = *reinterpret_cast<const float4*>(&As[k][n0]);
        float a[4] = {a4.x, a4.y, a4.z, a4.w};
        float w[8] = {w0.x, w0.y, w0.z, w0.w, w1.x, w1.y, w1.z, w1.w};
#pragma unroll
        for (int i = 0; i < 4; ++i)
#pragma unroll
            for (int j = 0; j < 8; ++j) acc[i][j] += a[i] * w[j];
    }

    const bool isY = (j0 < D);
    const int zj = isY ? j0 : (j0 - D);
    float bj[8];
#pragma unroll
    for (int j = 0; j < 8; ++j) bj[j] = isY ? 0.f : bias[zj + j];
    uint32* dstT = isY ? ybf : zbf;

#pragma unroll
    for (int i = 0; i < 4; ++i) {
        int node = base + n0 + i;
        if (node < N_NODES) {
            float v0 = acc[i][0] + bj[0], v1 = acc[i][1] + bj[1];
            float v2 = acc[i][2] + bj[2], v3 = acc[i][3] + bj[3];
            float v4 = acc[i][4] + bj[4], v5 = acc[i][5] + bj[5];
            float v6 = acc[i][6] + bj[6], v7 = acc[i][7] + bj[7];
            uint32 p0 = f2bf_rne(v0) | (f2bf_rne(v1) << 16);
            uint32 p1 = f2bf_rne(v2) | (f2bf_rne(v3) << 16);
            uint32 p2 = f2bf_rne(v4) | (f2bf_rne(v5) << 16);
            uint32 p3 = f2bf_rne(v6) | (f2bf_rne(v7) << 16);
            *reinterpret_cast<uint4*>(&dstT[node * (D / 2) + (zj >> 1)]) =
                make_uint4(p0, p1, p2, p3);
        }
    }
}

// -------- sparse part: out[i] = act(z[i] + inv*sum y[slots]) --------
// Wave = 1 node; half-wave 0 takes even slots, half-wave 1 odd slots.
// Lane loads uint (2 bf16 feats) -> 256B/request covering 2 edges.
// OUT_BF16: write packed bf16 row (32 uints) instead of 64 floats.
template <int RELU, int OUT_BF16>
__global__ __launch_bounds__(256, 8) void gather_mean(const uint32* __restrict__ ybf,
                                                      const uint32* __restrict__ zbf,
                                                      const int* __restrict__ slots,
                                                      const int* __restrict__ cnt,
                                                      void* __restrict__ outv) {
    int node = blockIdx.x * 4 + (threadIdx.x >> 6);   // wave-uniform
    if (node >= N_NODES) return;
    const int lane = threadIdx.x & 63;
    const int half = lane >> 5;
    const int fp = lane & 31;                          // feature-pair index
    int nodeu = __builtin_amdgcn_readfirstlane(node);
    int c = cnt[nodeu];                                // scalar load
    float inv = 1.0f / fmaxf((float)c, 1.0f);
    int cc = (c > SLOT_CAP) ? SLOT_CAP : c;
    const int* sl = &slots[nodeu * SLOT_CAP];
    uint32 zu = zbf[nodeu * (D / 2) + fp];             // issue early

    float ax[8], ay[8];
#pragma unroll
    for (int i = 0; i < 8; ++i) { ax[i] = 0.f; ay[i] = 0.f; }

    int k = 0;
    for (; k + 16 <= cc; k += 16) {                    // 16 slots per round
        int s[8];
#pragma unroll
        for (int i = 0; i < 8; ++i) s[i] = sl[k + 2 * i + half];
        uint32 v[8];
#pragma unroll
        for (int i = 0; i < 8; ++i) v[i] = ybf[s[i] * (D / 2) + fp];
#pragma unroll
        for (int i = 0; i < 8; ++i) {
            ax[i] += __uint_as_float(v[i] << 16);
            ay[i] += __uint_as_float(v[i] & 0xffff0000u);
        }
    }
    for (; k + 2 <= cc; k += 2) {                      // pair tail
        int s = sl[k + half];
        uint32 v = ybf[s * (D / 2) + fp];
        ax[0] += __uint_as_float(v << 16);
        ay[0] += __uint_as_float(v & 0xffff0000u);
    }
    if (k < cc) {                                      // odd last slot: half 0 only
        int s = sl[k];
        uint32 v = ybf[s * (D / 2) + fp];
        if (half == 0) {
            ax[1] += __uint_as_float(v << 16);
            ay[1] += __uint_as_float(v & 0xffff0000u);
        }
    }

    float sx = ((ax[0] + ax[4]) + (ax[1] + ax[5])) + ((ax[2] + ax[6]) + (ax[3] + ax[7]));
    float sy = ((ay[0] + ay[4]) + (ay[1] + ay[5])) + ((ay[2] + ay[6]) + (ay[3] + ay[7]));
    sx += __shfl_xor(sx, 32);                          // merge even/odd halves
    sy += __shfl_xor(sy, 32);

    float ox = __uint_as_float(zu << 16) + inv * sx;
    float oy = __uint_as_float(zu & 0xffff0000u) + inv * sy;
    if (RELU) { ox = fmaxf(ox, 0.f); oy = fmaxf(oy, 0.f); }
    if (half == 0) {
        if (OUT_BF16) {
            uint32 p = f2bf_rne(ox) | (f2bf_rne(oy) << 16);
            ((uint32*)outv)[node * (D / 2) + fp] = p;
        } else {
            float2 o; o.x = ox; o.y = oy;
            reinterpret_cast<float2*>((float*)outv + node * D)[fp] = o;
        }
    }
}

extern "C" void kernel_launch(void* const* d_in, const int* in_sizes, int n_in,
                              void* d_out, int out_size, void* d_ws, size_t ws_size,
                              hipStream_t stream) {
    const float* x   = (const float*)d_in[0];
    const int*   ei  = (const int*)d_in[1];
    const float* W1l = (const float*)d_in[2];
    const float* b1  = (const float*)d_in[3];
    const float* W1r = (const float*)d_in[4];
    const float* W2l = (const float*)d_in[5];
    const float* b2  = (const float*)d_in[6];
    const float* W2r = (const float*)d_in[7];
    float* out = (float*)d_out;

    const int* src = ei;            // edge_index[0]
    const int* dst = ei + N_EDGES;  // edge_index[1]

    // Workspace (~58 MB):
    //   cnt   [0, 400000)
    //   slots [400000, 19600000)
    //   bcnt  [19600000, 19600800)
    //   buf   [19600800, +9.63MB)   -- UNION with ybf (buf dead before GEMM1)
    //   ybf   [19600800, +12.8MB)   bf16 y table, 128B/row
    //   zbf   [32400800, +12.8MB)   bf16 z table, 128B/row
    //   h1b   [45200800, +12.8MB)   bf16 h1 table, 128B/row
    char* ws = (char*)d_ws;
    int*    cnt   = (int*)ws;
    int*    slots = (int*)(ws + 400000);
    int*    bcnt  = (int*)(ws + 19600000);
    int*    buf   = (int*)(ws + 19600800);
    uint32* ybf   = (uint32*)(ws + 19600800);
    uint32* zbf   = (uint32*)(ws + 32400800);
    uint32* h1b   = (uint32*)(ws + 45200800);

    // --- adjacency build ---
    (void)hipMemsetAsync(bcnt, 0, NBKT * 4, stream);
    bucket_pass<<<P1_GRID, P1_BLOCK, 0, stream>>>(src, dst, bcnt, buf);
    slots_pass<<<NBKT, P2_BLOCK, 0, stream>>>(buf, bcnt, cnt, slots);

    int gemm_grid   = (N_NODES + GEMM_TM - 1) / GEMM_TM;   // 1563
    int gather_grid = (N_NODES + 3) / 4;                   // 25000

    // layer 1 (fp32 x in, bf16 h1 out)
    yz_gemm<0><<<gemm_grid, 256, 0, stream>>>(x, W1l, W1r, b1, ybf, zbf);
    gather_mean<1, 1><<<gather_grid, 256, 0, stream>>>(ybf, zbf, slots, cnt, h1b);
    // layer 2 (bf16 h1 in, fp32 out)
    yz_gemm<1><<<gemm_grid, 256, 0, stream>>>(h1b, W2l, W2r, b2, ybf, zbf);
    gather_mean<0, 0><<<gather_grid, 256, 0, stream>>>(ybf, zbf, slots, cnt, out);
}